// Round 6
// baseline (117.612 us; speedup 1.0000x reference)
//
#include <hip/hip_runtime.h>

#define WL 512   // window_len (t and o dims)
#define NV 64    // n_var
#define LR 16    // low rank
#define NB 512   // batch

// ============================================================================
// MEASUREMENT ROUND: kernels are byte-equivalent to the best (48.8us, R2)
// version, but each repeats its body internally (K1 x3, K2 x2) computing
// identical results each rep. Purpose: push each dispatch above the harness
// fill kernels' ~39.5us so our kernels' rocprof counters finally surface in
// the top-5 table. asm "memory" clobbers prevent cross-rep CSE.
// Readout: K1 VALUBusy/FETCH; K2 FETCH (x re-read: L3 or HBM?), VALUBusy, Occ.
// ============================================================================

__device__ __forceinline__ float tanh_fast(float x) {
    float e = __expf(2.0f * x);
    return 1.0f - 2.0f / (e + 1.0f);
}

// K1: tmp[b,k,v] = sum_t tanh(g[v]*x[b,t,v]) * A[t,k]   ([b,k,v] layout, as R2)
__global__ __launch_bounds__(512, 4) void k_tmp(
    const float* __restrict__ x, const float* __restrict__ gating,
    const float* __restrict__ A, float* __restrict__ tmp)
{
    __shared__ float red[8 * LR * NV];  // 32 KiB
    const int tid = threadIdx.x;
    const int b = blockIdx.x;

    const int v = tid & 63;
    const int tg = __builtin_amdgcn_readfirstlane(tid >> 6);
    const float g = gating[v];

    const float* xb = x + (size_t)b * (WL * NV) + (size_t)tg * 64 * NV + v;
    const float* Abase = A + (size_t)tg * 64 * LR;

    for (int rep = 0; rep < 3; ++rep) {
        asm volatile("" ::: "memory");   // defeat cross-rep CSE of x/A loads

        float acc[LR];
#pragma unroll
        for (int k = 0; k < LR; ++k) acc[k] = 0.f;

#pragma unroll 4
        for (int i = 0; i < 64; ++i) {
            const float x1 = tanh_fast(g * xb[i * NV]);      // 256B/wave, coalesced
            const float* Ar = Abase + i * LR;                // wave-uniform -> s_load
#pragma unroll
            for (int k = 0; k < LR; ++k) acc[k] = fmaf(x1, Ar[k], acc[k]);
        }

#pragma unroll
        for (int k = 0; k < LR; ++k) red[(tg * LR + k) * NV + v] = acc[k];
        __syncthreads();
#pragma unroll
        for (int p = tid; p < LR * NV; p += 512) {
            float s = 0.f;
#pragma unroll
            for (int t = 0; t < 8; ++t) s += red[t * (LR * NV) + p];
            tmp[(size_t)b * (LR * NV) + p] = s;
        }
        __syncthreads();  // rep boundary: reduce-phase readers done before next rrow write
    }
}

// K2: out[b,o,v] = x[b,o,v] + bias[o,v] + sum_k tmp[b,k,v]*B[k,o,v]
// grid = (64 b-chunks of 8) x (32 o-tiles of 16), block = 256 (4 waves) — as R2
__global__ __launch_bounds__(256, 4) void k_out(
    const float* __restrict__ x, const float* __restrict__ bias,
    const float* __restrict__ Bm, const float* __restrict__ tmp,
    float* __restrict__ out)
{
    const int tid = threadIdx.x;
    const int v = tid & 63;
    const int og = tid >> 6;
    const int o_base = blockIdx.y * 16 + og * 4;
    const int b0 = blockIdx.x * 8;

    float Breg[4][LR];
#pragma unroll
    for (int j = 0; j < 4; ++j) {
        const int o = o_base + j;
#pragma unroll
        for (int k = 0; k < LR; ++k)
            Breg[j][k] = Bm[((size_t)k * WL + o) * NV + v];  // 256B/wave, coalesced
    }
    float breg[4];
#pragma unroll
    for (int j = 0; j < 4; ++j) breg[j] = bias[(o_base + j) * NV + v];

    for (int rep = 0; rep < 2; ++rep) {
        asm volatile("" ::: "memory");   // defeat cross-rep CSE of x/tmp loads

        for (int bi = 0; bi < 8; ++bi) {
            const int b = b0 + bi;
            const float* tb = tmp + (size_t)b * (LR * NV) + v;
            float tr[LR];
#pragma unroll
            for (int k = 0; k < LR; ++k) tr[k] = tb[k * NV];
            const float* xb = x + (size_t)b * WL * NV;
            float* ob = out + (size_t)b * WL * NV;
#pragma unroll
            for (int j = 0; j < 4; ++j) {
                const int o = o_base + j;
                float acc = breg[j];
#pragma unroll
                for (int k = 0; k < LR; ++k) acc += tr[k] * Breg[j][k];
                ob[o * NV + v] = xb[o * NV + v] + acc;
            }
        }
    }
}

extern "C" void kernel_launch(void* const* d_in, const int* in_sizes, int n_in,
                              void* d_out, int out_size, void* d_ws, size_t ws_size,
                              hipStream_t stream) {
    const float* x      = (const float*)d_in[0];  // [512,512,64,1]
    const float* gating = (const float*)d_in[1];  // [64]
    const float* bias   = (const float*)d_in[2];  // [512,64]
    const float* A      = (const float*)d_in[3];  // [512,16]
    const float* Bm     = (const float*)d_in[4];  // [16,512,64]
    float* out = (float*)d_out;
    float* tmp = (float*)d_ws;                    // 2 MiB scratch ([b,k,v])

    k_tmp<<<NB, 512, 0, stream>>>(x, gating, A, tmp);
    k_out<<<dim3(64, 32), 256, 0, stream>>>(x, bias, Bm, tmp, out);
}

// Round 7
// 47.850 us; speedup vs baseline: 2.4579x; 2.4579x over previous
//
#include <hip/hip_runtime.h>

#define WL 512   // window_len (t and o dims)
#define NV 64    // n_var
#define LR 16    // low rank
#define NB 512   // batch

__device__ __forceinline__ float tanh_fast(float x) {
    // tanh(x) = 1 - 2/(exp(2x)+1); exact at +-inf saturation, ~1e-7 abs err
    float e = __expf(2.0f * x);
    return 1.0f - 2.0f / (e + 1.0f);
}

// K1: tmp[b,k,v] = sum_t tanh(g[v]*x[b,t,v]) * A[t,k]
// grid = 512 (one block per b), block = 1024 threads (16 waves).
// Occupancy fix: K1 was grid-limited to 2 blocks/CU x 8 waves = 16 waves/CU;
// per-CU bytes in flight (~16KB) < Little's-law need (~22KB at 900cy, 24B/cy)
// -> measured 4.06 TB/s on a pure read stream. 1024-thread blocks keep
// 2 blocks/CU but double resident waves to 32/CU -> ~32KB in flight.
// launch_bounds(1024,8): 8 waves/SIMD -> VGPR capped at 64 (kernel needs ~45).
// thread: v = tid&63, t-group tg = tid>>6 (16 groups) owns 32 t's.
// A rows via wave-uniform (readfirstlane) addresses -> s_load/SGPR operands.
__global__ __launch_bounds__(1024, 8) void k_tmp(
    const float* __restrict__ x, const float* __restrict__ gating,
    const float* __restrict__ A, float* __restrict__ tmp)
{
    __shared__ float red[16 * LR * NV];  // 64 KiB (16 partials x 1024 (k,v))
    const int tid = threadIdx.x;
    const int b = blockIdx.x;

    const int v = tid & 63;
    const int tg = __builtin_amdgcn_readfirstlane(tid >> 6);
    const float g = gating[v];

    float acc[LR];
#pragma unroll
    for (int k = 0; k < LR; ++k) acc[k] = 0.f;

    const float* xb = x + (size_t)b * (WL * NV) + (size_t)tg * 32 * NV + v;
    const float* Abase = A + (size_t)tg * 32 * LR;

#pragma unroll 4
    for (int i = 0; i < 32; ++i) {
        const float x1 = tanh_fast(g * xb[i * NV]);      // 256B/wave, coalesced
        const float* Ar = Abase + i * LR;                // wave-uniform -> s_load
#pragma unroll
        for (int k = 0; k < LR; ++k) acc[k] = fmaf(x1, Ar[k], acc[k]);
    }

    // write 16 partials; lanes consecutive v -> conflict-free
#pragma unroll
    for (int k = 0; k < LR; ++k) red[(tg * LR + k) * NV + v] = acc[k];
    __syncthreads();

    // 1024 (k,v) pairs, exactly one per thread; coalesced store
    {
        const int p = tid;
        float s = 0.f;
#pragma unroll
        for (int t = 0; t < 16; ++t) s += red[t * (LR * NV) + p];
        tmp[(size_t)b * (LR * NV) + p] = s;
    }
}

// K2: out[b,o,v] = x[b,o,v] + bias[o,v] + sum_k tmp[b,k,v]*B[k,o,v]
// grid = (64 b-chunks of 8) x (32 o-tiles of 16), block = 256 (4 waves)
// thread: v = tid&63, wave og = tid>>6 owns o = oTile*16 + og*4 + j, j=0..3
// B slice held in registers (64 VGPR) and reused across the 8 batches.
// (byte-identical to the verified 48.8us R2 version; counters show it at
// ~3.9 TB/s mixed r/w with VALUBusy 22% -- near the mixed-stream ceiling)
__global__ __launch_bounds__(256, 4) void k_out(
    const float* __restrict__ x, const float* __restrict__ bias,
    const float* __restrict__ Bm, const float* __restrict__ tmp,
    float* __restrict__ out)
{
    const int tid = threadIdx.x;
    const int v = tid & 63;
    const int og = tid >> 6;
    const int o_base = blockIdx.y * 16 + og * 4;
    const int b0 = blockIdx.x * 8;

    float Breg[4][LR];
#pragma unroll
    for (int j = 0; j < 4; ++j) {
        const int o = o_base + j;
#pragma unroll
        for (int k = 0; k < LR; ++k)
            Breg[j][k] = Bm[((size_t)k * WL + o) * NV + v];  // 256B/wave, coalesced
    }
    float breg[4];
#pragma unroll
    for (int j = 0; j < 4; ++j) breg[j] = bias[(o_base + j) * NV + v];

    for (int bi = 0; bi < 8; ++bi) {
        const int b = b0 + bi;
        const float* tb = tmp + (size_t)b * (LR * NV) + v;
        float tr[LR];
#pragma unroll
        for (int k = 0; k < LR; ++k) tr[k] = tb[k * NV];     // L1/L2-resident
        const float* xb = x + (size_t)b * WL * NV;
        float* ob = out + (size_t)b * WL * NV;
#pragma unroll
        for (int j = 0; j < 4; ++j) {
            const int o = o_base + j;
            float acc = breg[j];
#pragma unroll
            for (int k = 0; k < LR; ++k) acc += tr[k] * Breg[j][k];
            ob[o * NV + v] = xb[o * NV + v] + acc;
        }
    }
}

extern "C" void kernel_launch(void* const* d_in, const int* in_sizes, int n_in,
                              void* d_out, int out_size, void* d_ws, size_t ws_size,
                              hipStream_t stream) {
    const float* x      = (const float*)d_in[0];  // [512,512,64,1]
    const float* gating = (const float*)d_in[1];  // [64]
    const float* bias   = (const float*)d_in[2];  // [512,64]
    const float* A      = (const float*)d_in[3];  // [512,16]
    const float* Bm     = (const float*)d_in[4];  // [16,512,64]
    float* out = (float*)d_out;
    float* tmp = (float*)d_ws;                    // 2 MiB scratch ([b,k,v])

    k_tmp<<<NB, 1024, 0, stream>>>(x, gating, A, tmp);
    k_out<<<dim3(64, 32), 256, 0, stream>>>(x, bias, Bm, tmp, out);
}